// Round 1
// baseline (82.911 us; speedup 1.0000x reference)
//
#include <hip/hip_runtime.h>
#include <math.h>

// One thread = one batch element. State = 16 fp32 in registers:
// idx = anc*8 + w1*4 + w2*2 + w3  (bit masks: ANC=8, W1=4, W2=2, W3=1).
//
// Oracle simplification: RY(t_b) on anc, phase-flip at (anc=1, data=b),
// RY(-t_b) == identity for d != b, and on d == b the 2x2 ancilla matrix is
//   [[cos t, -sin t], [-sin t, -cos t]]   (FULL angle t).
// Verified by direct matrix multiply RY(-t) * diag(1,-1) * RY(t).

#define RSQRT2 0.70710678118654752440f

#define HAD(m) do {                                               \
    _Pragma("unroll")                                             \
    for (int idx = 0; idx < 16; ++idx) {                          \
      if (!(idx & (m))) {                                         \
        float a_ = st[idx], b_ = st[idx | (m)];                   \
        st[idx]       = (a_ + b_) * RSQRT2;                       \
        st[idx | (m)] = (a_ - b_) * RSQRT2;                       \
      }                                                           \
    }                                                             \
  } while (0)

// CRY with ctrl mask cm, target mask tm, c = cos(theta/2), s = sin(theta/2).
#define CRY(cm, tm, cc, ss) do {                                  \
    _Pragma("unroll")                                             \
    for (int idx = 0; idx < 16; ++idx) {                          \
      if ((idx & (cm)) && !(idx & (tm))) {                        \
        float a_ = st[idx], b_ = st[idx | (tm)];                  \
        st[idx]        = (cc) * a_ - (ss) * b_;                   \
        st[idx | (tm)] = (ss) * a_ + (cc) * b_;                   \
      }                                                           \
    }                                                             \
  } while (0)

__global__ __launch_bounds__(256) void gqhan_kernel(
    const float* __restrict__ x,
    const float* __restrict__ theta_fo,
    const float* __restrict__ theta_ado,
    float* __restrict__ out, int B)
{
  // Per-block trig precompute (broadcast via LDS; 14 sincos per block).
  __shared__ float cf[8], sf[8];   // cos/sin of FULL theta_fo
  __shared__ float ca[6], sa[6];   // cos/sin of theta_ado / 2
  int t = threadIdx.x;
  if (t < 8) {
    float th = theta_fo[t];
    cf[t] = cosf(th);
    sf[t] = sinf(th);
  } else if (t < 14) {
    float th = 0.5f * theta_ado[t - 8];
    ca[t - 8] = cosf(th);
    sa[t - 8] = sinf(th);
  }
  __syncthreads();

  int i = blockIdx.x * blockDim.x + threadIdx.x;
  if (i >= B) return;

  // Load x row (8 floats) as two float4.
  const float4* xp = (const float4*)(x + (size_t)i * 8u);
  float4 lo = xp[0], hi = xp[1];
  float v[8] = {lo.x, lo.y, lo.z, lo.w, hi.x, hi.y, hi.z, hi.w};

  float n2 = 0.0f;
#pragma unroll
  for (int k = 0; k < 8; ++k) n2 += v[k] * v[k];
  float inv = rsqrtf(n2);

  float st[16];
#pragma unroll
  for (int k = 0; k < 8; ++k) { st[k] = v[k] * inv; st[8 + k] = 0.0f; }

  // ---- Flexible oracle: 8 disjoint 2x2 transforms on (b, 8+b) ----
#pragma unroll
  for (int b = 0; b < 8; ++b) {
    float c = cf[b], s = sf[b];
    float a0 = st[b], a1 = st[8 + b];
    st[b]     =  c * a0 - s * a1;
    st[8 + b] = -s * a0 - c * a1;
  }

  // ---- ADO ----
  HAD(4); HAD(2); HAD(1);                 // H on wires 1,2,3

  CRY(4, 2, ca[0], sa[0]);                // CRY(theta_ado[0]) ctrl w1 -> tgt w2
  CRY(2, 1, ca[1], sa[1]);                // ctrl w2 -> tgt w3
  CRY(1, 4, ca[2], sa[2]);                // ctrl w3 -> tgt w1

  // X-sandwiched MCZ == phase flip where all data wires are 0 (both anc)
  st[0] = -st[0];
  st[8] = -st[8];

  CRY(4, 2, ca[3], sa[3]);
  CRY(2, 1, ca[4], sa[4]);
  CRY(1, 4, ca[5], sa[5]);

  HAD(4); HAD(2); HAD(1);

  // ---- <Z> on wire 3: sum s^2 (bit0==0) - sum s^2 (bit0==1) ----
  float r = 0.0f;
#pragma unroll
  for (int idx = 0; idx < 16; ++idx) {
    float p = st[idx] * st[idx];
    r += (idx & 1) ? -p : p;
  }
  out[i] = r;
}

extern "C" void kernel_launch(void* const* d_in, const int* in_sizes, int n_in,
                              void* d_out, int out_size, void* d_ws, size_t ws_size,
                              hipStream_t stream) {
  const float* x         = (const float*)d_in[0];
  const float* theta_fo  = (const float*)d_in[1];
  const float* theta_ado = (const float*)d_in[2];
  float* out = (float*)d_out;
  int B = in_sizes[0] / 8;
  int block = 256;
  int grid = (B + block - 1) / block;
  gqhan_kernel<<<grid, block, 0, stream>>>(x, theta_fo, theta_ado, out, B);
}

// Round 2
// 80.000 us; speedup vs baseline: 1.0364x; 1.0364x over previous
//
#include <hip/hip_runtime.h>
#include <math.h>

// One thread = one batch element. State = 16 fp32 in registers:
// idx = anc*8 + w1*4 + w2*2 + w3  (bit masks: ANC=8, W1=4, W2=2, W3=1).
//
// Algebraic reductions vs the straightforward simulation:
//  * Oracle RY(t_b)->cond-phase->RY(-t_b) collapses to a 2x2 on (st[b],st[8+b])
//    with FULL angle t: [[c,-s],[-s,-c]]. Entering with st[8+b]==0 it is just
//    st[b]=c*v[b], st[8+b]=-s*v[b].
//  * Final H on w1,w2 commute with Z3-measurement -> dropped. H3 Z3 H3 = X3,
//    so we measure <X3> = 2*sum_{even idx} st[idx]*st[idx|1] before any final H.
//  * Normalization folded out: circuit is linear in x, so simulate unnormalized
//    and scale the final expectation by 1/||x||^2.

#define RSQRT2 0.70710678118654752440f

#define HAD(m) do {                                               \
    _Pragma("unroll")                                             \
    for (int idx = 0; idx < 16; ++idx) {                          \
      if (!(idx & (m))) {                                         \
        float a_ = st[idx], b_ = st[idx | (m)];                   \
        st[idx]       = (a_ + b_) * RSQRT2;                       \
        st[idx | (m)] = (a_ - b_) * RSQRT2;                       \
      }                                                           \
    }                                                             \
  } while (0)

// CRY: ctrl mask cm, target mask tm, c = cos(theta/2), s = sin(theta/2).
#define CRY(cm, tm, cc, ss) do {                                  \
    _Pragma("unroll")                                             \
    for (int idx = 0; idx < 16; ++idx) {                          \
      if ((idx & (cm)) && !(idx & (tm))) {                        \
        float a_ = st[idx], b_ = st[idx | (tm)];                  \
        st[idx]        = (cc) * a_ - (ss) * b_;                   \
        st[idx | (tm)] = (ss) * a_ + (cc) * b_;                   \
      }                                                           \
    }                                                             \
  } while (0)

__global__ __launch_bounds__(256) void gqhan_kernel(
    const float* __restrict__ x,
    const float* __restrict__ theta_fo,
    const float* __restrict__ theta_ado,
    float* __restrict__ out, int B)
{
  // Per-block trig precompute (broadcast via LDS; 14 sincos per block).
  __shared__ float cf[8], sf[8];   // cos/sin of FULL theta_fo
  __shared__ float ca[6], sa[6];   // cos/sin of theta_ado / 2
  int t = threadIdx.x;
  if (t < 8) {
    float th = theta_fo[t];
    cf[t] = cosf(th);
    sf[t] = sinf(th);
  } else if (t < 14) {
    float th = 0.5f * theta_ado[t - 8];
    ca[t - 8] = cosf(th);
    sa[t - 8] = sinf(th);
  }
  __syncthreads();

  int i = blockIdx.x * blockDim.x + threadIdx.x;
  if (i >= B) return;

  // Load x row (8 floats) as two float4 (32B-aligned).
  const float4* xp = (const float4*)(x + (size_t)i * 8u);
  float4 lo = xp[0], hi = xp[1];
  float v[8] = {lo.x, lo.y, lo.z, lo.w, hi.x, hi.y, hi.z, hi.w};

  float n2 = 0.0f;
#pragma unroll
  for (int k = 0; k < 8; ++k) n2 = fmaf(v[k], v[k], n2);

  // ---- Oracle on unnormalized amplitudes (ancilla starts |0>) ----
  float st[16];
#pragma unroll
  for (int b = 0; b < 8; ++b) {
    st[b]     =  cf[b] * v[b];
    st[8 + b] = -sf[b] * v[b];
  }

  // ---- ADO ----
  HAD(4); HAD(2); HAD(1);                 // H on wires 1,2,3

  CRY(4, 2, ca[0], sa[0]);                // CRY ctrl w1 -> tgt w2
  CRY(2, 1, ca[1], sa[1]);                // ctrl w2 -> tgt w3
  CRY(1, 4, ca[2], sa[2]);                // ctrl w3 -> tgt w1

  // X-sandwiched MCZ == phase flip where all data wires are 0 (both anc)
  st[0] = -st[0];
  st[8] = -st[8];

  CRY(4, 2, ca[3], sa[3]);
  CRY(2, 1, ca[4], sa[4]);
  CRY(1, 4, ca[5], sa[5]);

  // Final Hadamards dropped: measure <X3> instead of H3 + <Z3>;
  // H on w1,w2 commute with the wire-3 measurement.
  float r = 0.0f;
#pragma unroll
  for (int idx = 0; idx < 16; idx += 2)
    r = fmaf(st[idx], st[idx | 1], r);
  r = r + r;                               // cross-term factor 2

  // Undo the skipped input normalization: probabilities scale by ||x||^2.
  out[i] = r * __builtin_amdgcn_rcpf(n2);
}

extern "C" void kernel_launch(void* const* d_in, const int* in_sizes, int n_in,
                              void* d_out, int out_size, void* d_ws, size_t ws_size,
                              hipStream_t stream) {
  const float* x         = (const float*)d_in[0];
  const float* theta_fo  = (const float*)d_in[1];
  const float* theta_ado = (const float*)d_in[2];
  float* out = (float*)d_out;
  int B = in_sizes[0] / 8;
  int block = 256;
  int grid = (B + block - 1) / block;
  gqhan_kernel<<<grid, block, 0, stream>>>(x, theta_fo, theta_ado, out, B);
}